// Round 7
// baseline (461.479 us; speedup 1.0000x reference)
//
#include <hip/hip_runtime.h>
#include <hip/hip_bf16.h>

typedef unsigned short u16;
typedef u16 u16x4 __attribute__((ext_vector_type(4)));
typedef u16 u16x8 __attribute__((ext_vector_type(8)));
typedef __bf16 bf16x8 __attribute__((ext_vector_type(8)));
typedef float f32x4 __attribute__((ext_vector_type(4)));

__device__ __forceinline__ u16 f2bf(float f) {
  unsigned u = __float_as_uint(f);
  u += 0x7FFFu + ((u >> 16) & 1u);   // round-to-nearest-even
  return (u16)(u >> 16);
}
__device__ __forceinline__ float tanh_fast(float x) {
  float t = __expf(2.0f * x);
  return 1.0f - 2.0f / (t + 1.0f);
}
__device__ __forceinline__ float sigmoid_fast(float x) {
  return 1.0f / (1.0f + __expf(-x));
}
__device__ __forceinline__ void cvt4(const float* __restrict__ s, u16* __restrict__ d, int q) {
  float4 v = ((const float4*)s)[q];
  u16x4 o = { f2bf(v.x), f2bf(v.y), f2bf(v.z), f2bf(v.w) };
  ((u16x4*)d)[q] = o;
}

// Device-scope grid barrier (no cooperative API — R6's hipLaunchCooperativeKernel
// silently failed in this harness). Safe because grid(512) <= guaranteed
// co-residency: __launch_bounds__(256,2) => >=2 blocks/CU x 256 CUs.
// Release fence + device-scope atomic arrive; atomic spin + acquire fence depart.
__device__ __forceinline__ void grid_barrier(unsigned int* cnt, unsigned int target) {
  __syncthreads();
  if (threadIdx.x == 0) {
    __threadfence();                               // release: my stage's writes visible
    atomicAdd(cnt, 1u);                            // device-scope arrive
    while (atomicAdd(cnt, 0u) < target)            // device-scope coherent read
      __builtin_amdgcn_s_sleep(8);
    __threadfence();                               // acquire: others' writes visible
  }
  __syncthreads();
}

// ---------------- one BMxBN tile of C = A[M,K] * Bt[N,K]^T (R2/R5-proven core) ----------------
// VGPR-pipelined staging: tile k+1 loads issue right after the LDS-ready
// barrier and fly across the whole ds_read+MFMA section.
// EP 0: outb = bf16(tanh(x + bias[col]))
// EP 1: att = sigmoid(x + bias[col]); outf = att; sa = bf16(obs * att)
// EP 2: fused v-dot: atomicAdd(vout[row], sum_col tanh(x+bias)*W3[col]) — no C store
template <int BM, int BN, int EP>
__device__ __forceinline__ void gemm_tile(
    const u16* __restrict__ A, const u16* __restrict__ Bt,
    int N, int K, const float* __restrict__ bias,
    u16* __restrict__ outb, float* __restrict__ outf,
    const float* __restrict__ obs, u16* __restrict__ sa,
    const float* __restrict__ W3, const float* __restrict__ b3,
    float* __restrict__ vout,
    u16* As, u16* Bs, int bm, int bn) {
  constexpr int CA = BM / 64;
  constexpr int CB = BN / 64;
  constexpr int MI = BM / 32;
  constexpr int NJ = BN / 32;

  const int tid = threadIdx.x;
  const int lane = tid & 63;
  const int wave = tid >> 6;
  const int sr = tid >> 2;             // staging row 0..63
  const int c0 = (tid & 3) * 8;        // element offset in 32-wide K slab

  const u16* gA[CA];
  const u16* gB[CB];
#pragma unroll
  for (int q = 0; q < CA; ++q)
    gA[q] = A + (size_t)(bm * BM + sr + q * 64) * K + c0;
#pragma unroll
  for (int q = 0; q < CB; ++q)
    gB[q] = Bt + (size_t)(bn * BN + sr + q * 64) * K + c0;

  u16x8 pa[CA], pb[CB];
#pragma unroll
  for (int q = 0; q < CA; ++q) { pa[q] = *(const u16x8*)gA[q]; gA[q] += 32; }
#pragma unroll
  for (int q = 0; q < CB; ++q) { pb[q] = *(const u16x8*)gB[q]; gB[q] += 32; }

  const int wm = (wave >> 1) * (BM / 2);
  const int wn = (wave & 1) * (BN / 2);
  const int fr = lane & 15;
  const int koff = (lane >> 4) * 8;

  f32x4 acc[MI][NJ];
#pragma unroll
  for (int i = 0; i < MI; ++i)
#pragma unroll
    for (int j = 0; j < NJ; ++j)
      acc[i][j] = (f32x4){0.f, 0.f, 0.f, 0.f};

  const int T = K >> 5;
  for (int k = 0; k < T; ++k) {
    __syncthreads();                   // prev iter's LDS readers done (+vmcnt drain)
#pragma unroll
    for (int q = 0; q < CA; ++q) *(u16x8*)(As + (sr + q * 64) * 32 + c0) = pa[q];
#pragma unroll
    for (int q = 0; q < CB; ++q) *(u16x8*)(Bs + (sr + q * 64) * 32 + c0) = pb[q];
    __syncthreads();                   // LDS tile ready

    if (k + 1 < T) {                   // next-tile loads fly across MFMA section
#pragma unroll
      for (int q = 0; q < CA; ++q) { pa[q] = *(const u16x8*)gA[q]; gA[q] += 32; }
#pragma unroll
      for (int q = 0; q < CB; ++q) { pb[q] = *(const u16x8*)gB[q]; gB[q] += 32; }
    }

    bf16x8 a[MI], b[NJ];
#pragma unroll
    for (int i = 0; i < MI; ++i)
      a[i] = *(const bf16x8*)(As + (wm + i * 16 + fr) * 32 + koff);
#pragma unroll
    for (int j = 0; j < NJ; ++j)
      b[j] = *(const bf16x8*)(Bs + (wn + j * 16 + fr) * 32 + koff);
#pragma unroll
    for (int i = 0; i < MI; ++i)
#pragma unroll
      for (int j = 0; j < NJ; ++j)
        acc[i][j] = __builtin_amdgcn_mfma_f32_16x16x32_bf16(a[i], b[j], acc[i][j], 0, 0, 0);
  }

  // epilogue: row = bm*BM + wm + i*16 + (lane>>4)*4 + r, col = bn*BN + wn + j*16 + fr
  if constexpr (EP == 2) {
    float vpart[MI][4];
#pragma unroll
    for (int i = 0; i < MI; ++i)
#pragma unroll
      for (int r = 0; r < 4; ++r) vpart[i][r] = 0.f;
#pragma unroll
    for (int j = 0; j < NJ; ++j) {
      const int col = bn * BN + wn + j * 16 + fr;
      const float bv = bias[col];
      const float w3 = W3[col];
#pragma unroll
      for (int i = 0; i < MI; ++i)
#pragma unroll
        for (int r = 0; r < 4; ++r)
          vpart[i][r] += tanh_fast(acc[i][j][r] + bv) * w3;
    }
    const bool lead = (fr == 0);
    const bool addb = (bn == 0) && ((wave & 1) == 0);
#pragma unroll
    for (int i = 0; i < MI; ++i)
#pragma unroll
      for (int r = 0; r < 4; ++r) {
        float p = vpart[i][r];
        p += __shfl_xor(p, 8);
        p += __shfl_xor(p, 4);
        p += __shfl_xor(p, 2);
        p += __shfl_xor(p, 1);
        if (lead) {
          const int row = bm * BM + wm + i * 16 + (lane >> 4) * 4 + r;
          atomicAdd(vout + row, addb ? p + b3[0] : p);
        }
      }
  } else {
#pragma unroll
    for (int j = 0; j < NJ; ++j) {
      const int col = bn * BN + wn + j * 16 + fr;
      const float bv = bias[col];
#pragma unroll
      for (int i = 0; i < MI; ++i) {
#pragma unroll
        for (int r = 0; r < 4; ++r) {
          const int row = bm * BM + wm + i * 16 + (lane >> 4) * 4 + r;
          const float x = acc[i][j][r] + bv;
          const size_t idx = (size_t)row * N + col;
          if constexpr (EP == 0) {
            outb[idx] = f2bf(tanh_fast(x));
          } else {
            const float att = sigmoid_fast(x);
            outf[idx] = att;
            sa[idx] = f2bf(obs[idx] * att);
          }
        }
      }
    }
  }
}

// ---------------- mega-kernel: prep -> G1 -> G2 -> G3 -> G4+v, atomic grid barriers ----------------
__global__ __launch_bounds__(256, 2)
void mega(const float* __restrict__ obs, const float* __restrict__ We,
          const float* __restrict__ be, const float* __restrict__ attnW,
          const float* __restrict__ attnb,
          const float* __restrict__ W1, const float* __restrict__ b1,
          const float* __restrict__ W2, const float* __restrict__ b2,
          const float* __restrict__ W3, const float* __restrict__ b3,
          float* __restrict__ out,
          u16* __restrict__ We_b, u16* __restrict__ Wd,
          u16* __restrict__ W1_b, u16* __restrict__ W2_b,
          float* __restrict__ bd, u16* __restrict__ obs_b,
          u16* __restrict__ e_b, u16* __restrict__ sa_b,
          u16* __restrict__ h1_b, unsigned int* __restrict__ bar) {
  __shared__ __align__(16) u16 As[128 * 32];
  __shared__ __align__(16) u16 Bs[128 * 32];

  const int gtid = blockIdx.x * 256 + threadIdx.x;   // 0..131071
  const int b = blockIdx.x;                          // 0..511

  // ---- stage 0: fp32->bf16 casts, attn weight-diff, zero v ----
  if (gtid < 1024) ((float4*)out)[gtid] = (float4){0.f, 0.f, 0.f, 0.f};
  for (int q0 = gtid; q0 < 2883584; q0 += 131072) {
    int q = q0;
    if (q < 1048576) { cvt4(obs, obs_b, q); continue; }              // 4096x1024
    q -= 1048576;
    if (q < 131072) { cvt4(We, We_b, q); continue; }                 // 512x1024
    q -= 131072;
    if (q < 524288) { cvt4(W1, W1_b, q); continue; }                 // 2048x1024
    q -= 524288;
    if (q < 1048576) { cvt4(W2, W2_b, q); continue; }                // 2048x2048
    q -= 1048576;
    {                                                                // Wd: 1024x512
      int i0 = q * 4;
      int o = i0 >> 9, e0 = i0 & 511;
      const float* p = attnW + (size_t)o * 1024 + e0 * 2;
      float4 v0 = *(const float4*)p;
      float4 v1 = *(const float4*)(p + 4);
      u16x4 od = { f2bf(v0.y - v0.x), f2bf(v0.w - v0.z),
                   f2bf(v1.y - v1.x), f2bf(v1.w - v1.z) };
      *(u16x4*)(Wd + i0) = od;
      if (q < 256) {                                                 // bd: 1024
        float4 a0 = *(const float4*)(attnb + q * 8);
        float4 a1 = *(const float4*)(attnb + q * 8 + 4);
        float4 ob = { a0.y - a0.x, a0.w - a0.z, a1.y - a1.x, a1.w - a1.z };
        *(float4*)(bd + q * 4) = ob;
      }
    }
  }
  grid_barrier(bar + 0, 512);

  // ---- stage 1: e = tanh(obs @ We^T + be)  [4096,512], 64x64 tiles -> 512 blocks ----
  gemm_tile<64, 64, 0>(obs_b, We_b, 512, 1024, be, e_b, nullptr, nullptr,
                       nullptr, nullptr, nullptr, nullptr, As, Bs, b >> 3, b & 7);
  grid_barrier(bar + 1, 512);

  // ---- stage 2: att = sigmoid(e @ Wd^T + bd); sa = obs*att  [4096,1024], 128x64 -> 512 ----
  gemm_tile<128, 64, 1>(e_b, Wd, 1024, 512, bd, nullptr, out + 4096, obs,
                        sa_b, nullptr, nullptr, nullptr, As, Bs, b >> 4, b & 15);
  grid_barrier(bar + 2, 512);

  // ---- stage 3: h1 = tanh(sa @ W1^T + b1)  [4096,2048], 128x128 -> 512 ----
  gemm_tile<128, 128, 0>(sa_b, W1_b, 2048, 1024, b1, h1_b, nullptr, nullptr,
                         nullptr, nullptr, nullptr, nullptr, As, Bs, b >> 4, b & 15);
  grid_barrier(bar + 3, 512);

  // ---- stage 4: v = tanh(h1 @ W2^T + b2) @ W3 + b3 — h2 never stored ----
  gemm_tile<128, 128, 2>(h1_b, W2_b, 2048, 2048, b2, nullptr, nullptr, nullptr,
                         nullptr, W3, b3, out, As, Bs, b >> 4, b & 15);
}

extern "C" void kernel_launch(void* const* d_in, const int* in_sizes, int n_in,
                              void* d_out, int out_size, void* d_ws, size_t ws_size,
                              hipStream_t stream) {
  const float* obs   = (const float*)d_in[0];   // [4096,1024]
  const float* We    = (const float*)d_in[1];   // [512,1024]
  const float* be    = (const float*)d_in[2];   // [512]
  const float* attnW = (const float*)d_in[3];   // [1024,512,2]
  const float* attnb = (const float*)d_in[4];   // [1024,2]
  const float* W1    = (const float*)d_in[5];   // [2048,1024]
  const float* b1    = (const float*)d_in[6];   // [2048]
  const float* W2    = (const float*)d_in[7];   // [2048,2048]
  const float* b2    = (const float*)d_in[8];   // [2048]
  const float* W3    = (const float*)d_in[9];   // [1,2048]
  const float* b3    = (const float*)d_in[10];  // [1]
  float* out = (float*)d_out;                   // [4096] v, then [4096,1024] attention

  char* ws = (char*)d_ws;
  u16*   We_b  = (u16*)(ws + 0x00000000);   // 1 MB
  u16*   Wd_b  = (u16*)(ws + 0x00100000);   // 1 MB
  u16*   W1_b  = (u16*)(ws + 0x00200000);   // 4 MB
  u16*   W2_b  = (u16*)(ws + 0x00600000);   // 8 MB
  float* bd    = (float*)(ws + 0x00E00000); // 4 KB
  u16*   obs_b = (u16*)(ws + 0x00E01000);   // 8 MB
  u16*   e_b   = (u16*)(ws + 0x01601000);   // 4 MB
  u16*   sa_b  = (u16*)(ws + 0x01A01000);   // 8 MB
  u16*   h1_b  = (u16*)(ws + 0x02201000);   // 16 MB
  unsigned int* bar = (unsigned int*)(ws + 0x03201000); // 16 B barrier counters

  // barrier counters must start at 0 every call (ws is re-poisoned 0xAA)
  hipMemsetAsync(bar, 0, 4 * sizeof(unsigned int), stream);

  mega<<<512, 256, 0, stream>>>(obs, We, be, attnW, attnb, W1, b1, W2, b2,
                                W3, b3, out, We_b, Wd_b, W1_b, W2_b, bd,
                                obs_b, e_b, sa_b, h1_b, bar);
}

// Round 8
// 205.779 us; speedup vs baseline: 2.2426x; 2.2426x over previous
//
#include <hip/hip_runtime.h>
#include <hip/hip_bf16.h>

typedef unsigned short u16;
typedef u16 u16x4 __attribute__((ext_vector_type(4)));
typedef u16 u16x8 __attribute__((ext_vector_type(8)));
typedef __bf16 bf16x8 __attribute__((ext_vector_type(8)));
typedef float f32x4 __attribute__((ext_vector_type(4)));

__device__ __forceinline__ u16 f2bf(float f) {
  unsigned u = __float_as_uint(f);
  u += 0x7FFFu + ((u >> 16) & 1u);   // round-to-nearest-even
  return (u16)(u >> 16);
}
__device__ __forceinline__ float bf2f(u16 h) {
  return __uint_as_float(((unsigned)h) << 16);
}
__device__ __forceinline__ float tanh_fast(float x) {
  float t = __expf(2.0f * x);
  return 1.0f - 2.0f / (t + 1.0f);
}
__device__ __forceinline__ float sigmoid_fast(float x) {
  return 1.0f / (1.0f + __expf(-x));
}

// ---------------- fused prep: fp32->bf16 casts + attn weight-diff + zero v ----------------
__device__ __forceinline__ void cvt4(const float* __restrict__ s, u16* __restrict__ d, int q) {
  float4 v = ((const float4*)s)[q];
  u16x4 o = { f2bf(v.x), f2bf(v.y), f2bf(v.z), f2bf(v.w) };
  ((u16x4*)d)[q] = o;
}

__global__ __launch_bounds__(256)
void prep_kernel(const float* __restrict__ obs, const float* __restrict__ We,
                 const float* __restrict__ W1, const float* __restrict__ W2,
                 const float* __restrict__ aW, const float* __restrict__ ab,
                 u16* __restrict__ obs_b, u16* __restrict__ We_b,
                 u16* __restrict__ W1_b, u16* __restrict__ W2_b,
                 u16* __restrict__ Wd, float* __restrict__ bd,
                 float* __restrict__ vzero) {
  int q = blockIdx.x * 256 + threadIdx.x;          // quad (4-element) index
  if (q < 1024) ((float4*)vzero)[q] = (float4){0.f, 0.f, 0.f, 0.f};  // zero v[4096]
  if (q < 1048576) { cvt4(obs, obs_b, q); return; }                 // 4096*1024
  q -= 1048576;
  if (q < 131072) { cvt4(We, We_b, q); return; }                    // 512*1024
  q -= 131072;
  if (q < 524288) { cvt4(W1, W1_b, q); return; }                    // 2048*1024
  q -= 524288;
  if (q < 1048576) { cvt4(W2, W2_b, q); return; }                   // 2048*2048
  q -= 1048576;
  if (q < 131072) {                                                  // Wd: 1024*512
    int i0 = q * 4;
    int o = i0 >> 9, e0 = i0 & 511;
    const float* p = aW + (size_t)o * 1024 + e0 * 2;
    float4 v0 = *(const float4*)p;
    float4 v1 = *(const float4*)(p + 4);
    u16x4 od = { f2bf(v0.y - v0.x), f2bf(v0.w - v0.z),
                 f2bf(v1.y - v1.x), f2bf(v1.w - v1.z) };
    *(u16x4*)(Wd + i0) = od;
    if (q < 256) {                                                   // bd: 1024
      float4 a0 = *(const float4*)(ab + q * 8);
      float4 a1 = *(const float4*)(ab + q * 8 + 4);
      float4 ob = { a0.y - a0.x, a0.w - a0.z, a1.y - a1.x, a1.w - a1.z };
      *(float4*)(bd + q * 4) = ob;
    }
  }
}

// ---------------- bf16 MFMA GEMM, C = A[M,K] * Bt[N,K]^T, BK=64 ----------------
// R2-proven VGPR-pipelined staging, widened to 64-deep K slabs: 32 MFMAs per
// barrier pair (was 16) halves barrier/latency overhead per FLOP. LDS row
// stride padded to 72 elements (144 B -> 4-bank rotation/row: only free 2-way
// conflicts; VGPR staging permits padding, unlike glds).
// EP 0: outb = bf16(tanh(x + bias[col]))
// EP 1: att = sigmoid(x + bias[col]); outf = att; sa = bf16(obs_b * att)
// EP 2: fused v-dot: atomicAdd(vout[row], sum_col tanh(x+bias)*W3[col]) — no C store
template <int BM, int BN, int EP>
__global__ __launch_bounds__(256, 2)
void gemm_bt(const u16* __restrict__ A, const u16* __restrict__ Bt,
             int N, int K,
             const float* __restrict__ bias,
             u16* __restrict__ outb, float* __restrict__ outf,
             const u16* __restrict__ obsb, u16* __restrict__ sa,
             const float* __restrict__ W3, const float* __restrict__ b3,
             float* __restrict__ vout) {
  constexpr int LS = 72;               // padded LDS row stride (elements)
  constexpr int CA = BM / 32;          // staging passes (32 rows per pass)
  constexpr int CB = BN / 32;
  constexpr int MI = BM / 32;          // 16-row frags per wave
  constexpr int NJ = BN / 32;          // 16-col frags per wave

  __shared__ __align__(16) u16 As[BM * LS];
  __shared__ __align__(16) u16 Bs[BN * LS];

  const int tid = threadIdx.x;
  const int lane = tid & 63;
  const int wave = tid >> 6;
  const int bm = blockIdx.x, bn = blockIdx.y;

  const int r0 = tid >> 3;             // staging row 0..31
  const int kc = (tid & 7) * 8;        // element offset in 64-wide K slab

  const u16* gA[CA];
  const u16* gB[CB];
#pragma unroll
  for (int q = 0; q < CA; ++q)
    gA[q] = A + (size_t)(bm * BM + r0 + q * 32) * K + kc;
#pragma unroll
  for (int q = 0; q < CB; ++q)
    gB[q] = Bt + (size_t)(bn * BN + r0 + q * 32) * K + kc;

  u16x8 pa[CA], pb[CB];
#pragma unroll
  for (int q = 0; q < CA; ++q) { pa[q] = *(const u16x8*)gA[q]; gA[q] += 64; }
#pragma unroll
  for (int q = 0; q < CB; ++q) { pb[q] = *(const u16x8*)gB[q]; gB[q] += 64; }

  const int wm = (wave >> 1) * (BM / 2);
  const int wn = (wave & 1) * (BN / 2);
  const int fr = lane & 15;
  const int koff = (lane >> 4) * 8;

  f32x4 acc[MI][NJ];
#pragma unroll
  for (int i = 0; i < MI; ++i)
#pragma unroll
    for (int j = 0; j < NJ; ++j)
      acc[i][j] = (f32x4){0.f, 0.f, 0.f, 0.f};

  const int T = K >> 6;
  for (int k = 0; k < T; ++k) {
    __syncthreads();                   // prev iter's LDS readers done (+vmcnt drain)
#pragma unroll
    for (int q = 0; q < CA; ++q) *(u16x8*)(As + (r0 + q * 32) * LS + kc) = pa[q];
#pragma unroll
    for (int q = 0; q < CB; ++q) *(u16x8*)(Bs + (r0 + q * 32) * LS + kc) = pb[q];
    __syncthreads();                   // LDS tile ready

    if (k + 1 < T) {                   // next-tile loads fly across 32 MFMAs
#pragma unroll
      for (int q = 0; q < CA; ++q) { pa[q] = *(const u16x8*)gA[q]; gA[q] += 64; }
#pragma unroll
      for (int q = 0; q < CB; ++q) { pb[q] = *(const u16x8*)gB[q]; gB[q] += 64; }
    }

#pragma unroll
    for (int s = 0; s < 2; ++s) {      // two K=32 sub-steps per staged slab
      bf16x8 a[MI], b[NJ];
#pragma unroll
      for (int i = 0; i < MI; ++i)
        a[i] = *(const bf16x8*)(As + (wm + i * 16 + fr) * LS + s * 32 + koff);
#pragma unroll
      for (int j = 0; j < NJ; ++j)
        b[j] = *(const bf16x8*)(Bs + (wn + j * 16 + fr) * LS + s * 32 + koff);
#pragma unroll
      for (int i = 0; i < MI; ++i)
#pragma unroll
        for (int j = 0; j < NJ; ++j)
          acc[i][j] = __builtin_amdgcn_mfma_f32_16x16x32_bf16(a[i], b[j], acc[i][j], 0, 0, 0);
    }
  }

  // epilogue: row = bm*BM + wm + i*16 + (lane>>4)*4 + r, col = bn*BN + wn + j*16 + fr
  if constexpr (EP == 2) {
    float vpart[MI][4];
#pragma unroll
    for (int i = 0; i < MI; ++i)
#pragma unroll
      for (int r = 0; r < 4; ++r) vpart[i][r] = 0.f;
#pragma unroll
    for (int j = 0; j < NJ; ++j) {
      const int col = bn * BN + wn + j * 16 + fr;
      const float bv = bias[col];
      const float w3 = W3[col];
#pragma unroll
      for (int i = 0; i < MI; ++i)
#pragma unroll
        for (int r = 0; r < 4; ++r)
          vpart[i][r] += tanh_fast(acc[i][j][r] + bv) * w3;
    }
    const bool lead = (fr == 0);
    const bool addb = (bn == 0) && ((wave & 1) == 0);
#pragma unroll
    for (int i = 0; i < MI; ++i)
#pragma unroll
      for (int r = 0; r < 4; ++r) {
        float p = vpart[i][r];
        p += __shfl_xor(p, 8);
        p += __shfl_xor(p, 4);
        p += __shfl_xor(p, 2);
        p += __shfl_xor(p, 1);
        if (lead) {
          const int row = bm * BM + wm + i * 16 + (lane >> 4) * 4 + r;
          atomicAdd(vout + row, addb ? p + b3[0] : p);
        }
      }
  } else {
#pragma unroll
    for (int j = 0; j < NJ; ++j) {
      const int col = bn * BN + wn + j * 16 + fr;
      const float bv = bias[col];
#pragma unroll
      for (int i = 0; i < MI; ++i) {
#pragma unroll
        for (int r = 0; r < 4; ++r) {
          const int row = bm * BM + wm + i * 16 + (lane >> 4) * 4 + r;
          const float x = acc[i][j][r] + bv;
          const size_t idx = (size_t)row * N + col;
          if constexpr (EP == 0) {
            outb[idx] = f2bf(tanh_fast(x));
          } else {
            const float att = sigmoid_fast(x);
            outf[idx] = att;
            sa[idx] = f2bf(bf2f(obsb[idx]) * att);
          }
        }
      }
    }
  }
}

extern "C" void kernel_launch(void* const* d_in, const int* in_sizes, int n_in,
                              void* d_out, int out_size, void* d_ws, size_t ws_size,
                              hipStream_t stream) {
  const float* obs   = (const float*)d_in[0];   // [4096,1024]
  const float* We    = (const float*)d_in[1];   // [512,1024]
  const float* be    = (const float*)d_in[2];   // [512]
  const float* attnW = (const float*)d_in[3];   // [1024,512,2]
  const float* attnb = (const float*)d_in[4];   // [1024,2]
  const float* W1    = (const float*)d_in[5];   // [2048,1024]
  const float* b1    = (const float*)d_in[6];   // [2048]
  const float* W2    = (const float*)d_in[7];   // [2048,2048]
  const float* b2    = (const float*)d_in[8];   // [2048]
  const float* W3    = (const float*)d_in[9];   // [1,2048]
  const float* b3    = (const float*)d_in[10];  // [1]
  float* out = (float*)d_out;                   // [4096] v, then [4096,1024] attention

  char* ws = (char*)d_ws;
  u16*   We_b  = (u16*)(ws + 0x00000000);   // 1 MB
  u16*   Wd_b  = (u16*)(ws + 0x00100000);   // 1 MB
  u16*   W1_b  = (u16*)(ws + 0x00200000);   // 4 MB
  u16*   W2_b  = (u16*)(ws + 0x00600000);   // 8 MB
  float* bd    = (float*)(ws + 0x00E00000); // 4 KB
  u16*   obs_b = (u16*)(ws + 0x00E01000);   // 8 MB
  u16*   e_b   = (u16*)(ws + 0x01601000);   // 4 MB
  u16*   sa_b  = (u16*)(ws + 0x01A01000);   // 8 MB
  u16*   h1_b  = (u16*)(ws + 0x02201000);   // 16 MB (end ~50 MB; h2 never stored)

  // prep: all casts + attn weight prep + zero v, one launch
  prep_kernel<<<11264, 256, 0, stream>>>(obs, We, W1, W2, attnW, attnb,
                                         obs_b, We_b, W1_b, W2_b, Wd_b, bd, out);

  // G1: e = tanh(obs @ We^T + be)   [4096,512]  64x64 -> 512 blocks, 2/CU
  gemm_bt<64, 64, 0><<<dim3(64, 8), 256, 0, stream>>>(
      obs_b, We_b, 512, 1024, be, e_b, nullptr, nullptr, nullptr, nullptr, nullptr, nullptr);
  // G2: att = sigmoid(e @ Wd^T + bd); sa = obs*att   [4096,1024]  128x64 -> 512 blocks
  gemm_bt<128, 64, 1><<<dim3(32, 16), 256, 0, stream>>>(
      e_b, Wd_b, 1024, 512, bd, nullptr, out + 4096, obs_b, sa_b, nullptr, nullptr, nullptr);
  // G3: h1 = tanh(sa @ W1^T + b1)   [4096,2048]  128x128 -> 512 blocks
  gemm_bt<128, 128, 0><<<dim3(32, 16), 256, 0, stream>>>(
      sa_b, W1_b, 2048, 1024, b1, h1_b, nullptr, nullptr, nullptr, nullptr, nullptr, nullptr);
  // G4+v: v = tanh(h1 @ W2^T + b2) @ W3 + b3 — fused, h2 never stored
  gemm_bt<128, 128, 2><<<dim3(32, 16), 256, 0, stream>>>(
      h1_b, W2_b, 2048, 2048, b2, nullptr, nullptr, nullptr, nullptr, W3, b3, out);
}